// Round 10
// baseline (5175.125 us; speedup 1.0000x reference)
//
#include <hip/hip_runtime.h>
#include <math.h>

typedef __bf16 bf16_t;
typedef __bf16 bfrag  __attribute__((ext_vector_type(8)));  // 8 bf16 (MFMA A/B frag)
typedef __bf16 b4     __attribute__((ext_vector_type(4)));  // 4 bf16 = 8B vector store
typedef __bf16 b2v    __attribute__((ext_vector_type(2)));  // 2 bf16 = 4B vector
typedef float  f32x4  __attribute__((ext_vector_type(4)));  // MFMA C/D frag

static constexpr int LY  = 5;
static constexpr int H   = 256;
static constexpr int NN  = 200000;
static constexpr int EE  = 400000;
static constexpr int GG  = 8000;
static constexpr int NPG = 25;
static constexpr int CAP = 24;   // max buffered in-edges/node (Poisson(2): P(>24) ~ 1e-17)
static constexpr int MROW = 64;                  // rows per fused-MLP block
static constexpr int NBLK_NODE = NN / MROW;      // 3125
static constexpr int NBLK_VN   = GG / MROW;      // 125

// tanh-approx GELU (~8 VALU ops; |delta| vs exact erf-gelu ~3e-4 absolute)
__device__ __forceinline__ float gelu_f(float x) {
    const float y = 0.7978845608028654f * x * (1.0f + 0.044715f * x * x);
    const float e = __expf(2.0f * y);
    const float t = 1.0f - 2.0f / (e + 1.0f);
    return 0.5f * x * (1.0f + t);
}

// ---- barrier helpers: NO vm-drain barriers (counted vmcnt) ----
__device__ __forceinline__ void lgkm_bar() {
    asm volatile("s_waitcnt lgkmcnt(0)" ::: "memory");
    __builtin_amdgcn_sched_barrier(0);
    __builtin_amdgcn_s_barrier();
    __builtin_amdgcn_sched_barrier(0);
}
template <int N>
__device__ __forceinline__ void vm_bar() {
    if constexpr (N == 0) asm volatile("s_waitcnt vmcnt(0)" ::: "memory");
    else                  asm volatile("s_waitcnt vmcnt(1)" ::: "memory");
    __builtin_amdgcn_sched_barrier(0);
    __builtin_amdgcn_s_barrier();
    __builtin_amdgcn_sched_barrier(0);
}

// ---------------- diagnostics ----------------
__global__ void k_fill(float* __restrict__ out, float v, int n) {
    const int i = blockIdx.x * 256 + threadIdx.x;
    if (i < n) out[i] = v;
}

// ---------------- dtype detection ----------------
__global__ void k_detect(const void* __restrict__ probe, int* __restrict__ flag) {
    const bf16_t* p = (const bf16_t*)probe;
    int bad = 0;
    for (int i = threadIdx.x; i < 256; i += 64) {
        const float v = (float)p[i];
        if (!(v == v) || fabsf(v) > 1000.0f) bad = 1;
    }
    const int any = __any(bad) ? 1 : 0;
    if (threadIdx.x == 0) *flag = any;
}

// ---------------- batched param conversion (1 launch) ----------------
struct CvtJobs {
    const void* src[18];
    bf16_t*     dst[18];
    int         pfx[19];
    int         njobs;
};
__global__ void k_cvt_all(CvtJobs J, const int* __restrict__ flag) {
    const int i = blockIdx.x * 256 + threadIdx.x;
    if (i >= J.pfx[J.njobs]) return;
    int j = 0;
    while (i >= J.pfx[j + 1]) ++j;
    const int loc = i - J.pfx[j];
    if (*flag) J.dst[j][loc] = (bf16_t)((const float*)J.src[j])[loc];
    else       J.dst[j][loc] = ((const bf16_t*)J.src[j])[loc];
}

// ---------------- batched weight transpose (1 launch) ----------------
struct TpJobs {
    const void* s32[22];
    const void* s16[22];
    bf16_t*     dst[22];
    int R[22], C[22];
    int pfx[23];
    int njobs;
};
__global__ void k_tp_all(TpJobs J, const int* __restrict__ flag) {
    __shared__ bf16_t t[32][33];
    const int tile = blockIdx.x;
    int j = 0;
    while (tile >= J.pfx[j + 1]) ++j;
    const int tl = tile - J.pfx[j];
    const int C = J.C[j], R = J.R[j];
    const int ntx = C / 32;
    const int c0 = (tl % ntx) * 32, r0 = (tl / ntx) * 32;
    const int f = *flag;
    const int tx = threadIdx.x & 31, ty = threadIdx.x >> 5;
    #pragma unroll
    for (int i = 0; i < 4; ++i) {
        const int r = ty + i * 8;
        const size_t idx = (size_t)(r0 + r) * C + c0 + tx;
        t[r][tx] = f ? (bf16_t)((const float*)J.s32[j])[idx] : ((const bf16_t*)J.s16[j])[idx];
    }
    __syncthreads();
    #pragma unroll
    for (int i = 0; i < 4; ++i) {
        const int r = ty + i * 8;
        J.dst[j][(size_t)(c0 + r) * R + r0 + tx] = t[tx][r];
    }
}

// ---------------- init ----------------
__global__ void k_init_h(const int* __restrict__ x, const bf16_t* __restrict__ atom,
                         bf16_t* __restrict__ h) {
    const size_t idx = (size_t)blockIdx.x * 256 + threadIdx.x;
    const int row = (int)(idx >> 8), col = (int)(idx & 255);
    h[idx] = atom[(size_t)x[row] * H + col];
}

__global__ void k_init_vn(const bf16_t* __restrict__ vne, float* __restrict__ vn) {
    const size_t idx = (size_t)blockIdx.x * 256 + threadIdx.x;
    vn[idx] = (float)vne[idx & 255];
}

// ---------------- edge bucket build (packed src|attr slots) ----------------
__global__ void k_zero_cnt(int* __restrict__ cnt) {
    const int i = blockIdx.x * 256 + threadIdx.x;
    if (i < NN) cnt[i] = 0;
}

// slots hold src | (attr << 18)  (src < 2^18 since NN=200000 < 262144; attr < 8)
__global__ void k_bucket(const int* __restrict__ ei, const int* __restrict__ ea,
                         int* __restrict__ cnt, int* __restrict__ slots) {
    const int e = blockIdx.x * 256 + threadIdx.x;
    if (e >= EE) return;
    const int d = ei[EE + e];
    const int s = ei[e];
    const int a = ea[e];
    const int slot = atomicAdd(&cnt[d], 1);
    if (slot < CAP) slots[(size_t)d * CAP + slot] = s | (a << 18);
}

// ---------------- fused addvn + segment_max (block = 1 graph, bf16x2 lanes) ----------------
__global__ void k_addvn_segmax(bf16_t* __restrict__ h, const float* __restrict__ vn,
                               bf16_t* __restrict__ vp, int do_max) {
    const int g = blockIdx.x, t = threadIdx.x;   // 128 threads; cols 2t, 2t+1
    const float2 v = *(const float2*)(vn + (size_t)g * H + 2 * t);
    float mx0 = -1e30f, mx1 = -1e30f;
    #pragma unroll 5
    for (int i = 0; i < NPG; ++i) {
        bf16_t* p = h + ((size_t)g * NPG + i) * H + 2 * t;
        const b2v hv = *(const b2v*)p;
        const float h0 = (float)hv[0] + v.x;
        const float h1 = (float)hv[1] + v.y;
        b2v o; o[0] = (bf16_t)h0; o[1] = (bf16_t)h1;
        *(b2v*)p = o;
        mx0 = fmaxf(mx0, h0); mx1 = fmaxf(mx1, h1);
    }
    if (do_max) {
        b2v o; o[0] = (bf16_t)mx0; o[1] = (bf16_t)mx1;
        *(b2v*)(vp + (size_t)g * H + 2 * t) = o;
    }
}

__global__ void k_graphsum(const bf16_t* __restrict__ h, bf16_t* __restrict__ hg) {
    const int g = blockIdx.x, t = threadIdx.x;   // 128 threads
    float s0 = 0.0f, s1 = 0.0f;
    #pragma unroll 5
    for (int i = 0; i < NPG; ++i) {
        const b2v hv = *(const b2v*)(h + ((size_t)g * NPG + i) * H + 2 * t);
        s0 += (float)hv[0]; s1 += (float)hv[1];
    }
    b2v o; o[0] = (bf16_t)s0; o[1] = (bf16_t)s1;
    *(b2v*)(hg + (size_t)g * H + 2 * t) = o;
}

__global__ void k_norm(const float* __restrict__ z, float* __restrict__ out) {
    const int row = blockIdx.x, t = threadIdx.x;
    const size_t idx = (size_t)row * H + t;
    const float v = z[idx];
    float q = v * v;
    #pragma unroll
    for (int o = 32; o > 0; o >>= 1) q += __shfl_xor(q, o, 64);
    __shared__ float rq[4];
    const int wave = t >> 6, lane = t & 63;
    if (lane == 0) rq[wave] = q;
    __syncthreads();
    q = rq[0] + rq[1] + rq[2] + rq[3];
    out[idx] = v * rsqrtf(q);
}

// ---------------- fused GATHER + MLP dual, M=64 (R9 core, halved stall traversals) ----------------
// M=64 rows/block, 1024 threads = 16 waves: wrow = wave>>3 picks the 32-row
// half, wcol = wave&7 the col-group — per-wave code is identical to R9's
// (xa[8][2], 2 MFMAs/unit, ~64 VGPR; no R8 pressure spike). The SAME 128-unit
// 8 KB counted-vmcnt weight pipeline is staged by waves 0-7 only (wave-uniform
// branch; waves 8-15 pass vmcnt(1) trivially and sync at the barrier) but
// feeds 2x the MFMA work; block count halves (6500 -> 3250) so the number of
// latency-bound pipeline traversals halves. This is R4's geometry WITH R5's
// counted waits — R4 failed on drain-barriers, which counted vmcnt removes.
// LDS = 128 KB hid (X-tile aliases first 32 KB) + 16 KB wbuf = 144 KB ->
// 1 block/CU, 16 waves. Gather is cooperative (64 nodes x 16 lanes), phase-
// separated from the one-shot xa load (no spill). h ping-pongs (hin/hout).
__launch_bounds__(1024, 1)
__global__ void k_mlp_dual(const bf16_t* __restrict__ hin, const bf16_t* __restrict__ Xv,
                           const int* __restrict__ cnt, const int* __restrict__ slots,
                           const bf16_t* __restrict__ bondl, const bf16_t* __restrict__ epsb, int lidx,
                           const bf16_t* __restrict__ nW1T, const bf16_t* __restrict__ vW1T,
                           const bf16_t* __restrict__ nb1, const bf16_t* __restrict__ vb1,
                           const bf16_t* __restrict__ nlng, const bf16_t* __restrict__ vlng,
                           const bf16_t* __restrict__ nlnb, const bf16_t* __restrict__ vlnb,
                           const bf16_t* __restrict__ nW2T, const bf16_t* __restrict__ vW2T,
                           const bf16_t* __restrict__ nb2, const bf16_t* __restrict__ vb2,
                           const bf16_t* __restrict__ g2, const bf16_t* __restrict__ b2ln,
                           bf16_t* __restrict__ hout, float* __restrict__ vnacc,
                           int gelu_flag, int nblk_node, int has_vn) {
    constexpr int HID = 1024;
    __shared__ __align__(16) bf16_t hid[MROW * HID];  // 128 KB (first 32 KB doubles as X-tile)
    __shared__ __align__(16) bf16_t wbuf[8192];       // 16 KB = 2 x 8 KB units
    bf16_t* xbuf = hid;                               // X-tile alias: 64 rows x 256 (swizzled)
    const int tid  = threadIdx.x;
    const int lane = tid & 63, wave = tid >> 6;       // wave 0..15
    const int c16  = lane & 15, quad = lane >> 4;
    const int wcol = wave & 7;                        // col-group
    const int wrow = wave >> 3;                       // row half

    const bool is_node = (int)blockIdx.x < nblk_node;
    const size_t rowblk = is_node ? (size_t)blockIdx.x * MROW
                                  : (size_t)((int)blockIdx.x - nblk_node) * MROW;
    const bf16_t* W1T  = is_node ? nW1T : vW1T;
    const bf16_t* W2T  = is_node ? nW2T : vW2T;
    const bf16_t* b1   = is_node ? nb1  : vb1;
    const bf16_t* lng  = is_node ? nlng : vlng;
    const bf16_t* lnb  = is_node ? nlnb : vlnb;
    const bf16_t* b2   = is_node ? nb2  : vb2;

    // ---- bias preload (R5 discipline: no stray global loads in GEMM loops) ----
    b4 bias1[8], bias2[2];
    #pragma unroll
    for (int c = 0; c < 8; ++c)
        bias1[c] = *(const b4*)(b1 + c * 128 + wcol * 16 + quad * 4);
    #pragma unroll
    for (int cp = 0; cp < 2; ++cp)
        bias2[cp] = *(const b4*)(b2 + cp * 128 + wcol * 16 + quad * 4);

    // ---- phase 1: build X-tile in LDS (swizzled: row r, 16B-seg j at j^(r&7)) ----
    if (is_node) {
        // cooperative gather: wave handles 4 nodes; 16 lanes per node; 64 nodes total.
        const float eps1 = 1.0f + (float)epsb[lidx];
        const int n_sub  = lane >> 4;           // 0..3
        const int lane16 = lane & 15;           // 0..15
        const int nidx   = wave * 4 + n_sub;    // 0..63
        const int node   = (int)rowblk + nidx;
        int deg = cnt[node];
        if (deg > CAP) deg = CAP;
        const int sbase = node * CAP;
        float acc[2][8];
        #pragma unroll
        for (int hh = 0; hh < 2; ++hh)
            #pragma unroll
            for (int k = 0; k < 8; ++k) acc[hh][k] = 0.f;
        for (int i = 0; i < deg; ++i) {
            const int p  = slots[sbase + i];
            const int s  = p & 0x3FFFF;
            const int at = p >> 18;
            #pragma unroll
            for (int hh = 0; hh < 2; ++hh) {
                const int cb = hh * 128 + lane16 * 8;
                const bfrag hv = *(const bfrag*)(hin + (size_t)s * 256 + cb);
                const bfrag bv = *(const bfrag*)(bondl + (size_t)at * 256 + cb);
                #pragma unroll
                for (int k = 0; k < 8; ++k)
                    acc[hh][k] += gelu_f((float)hv[k] + (float)bv[k]);
            }
        }
        #pragma unroll
        for (int hh = 0; hh < 2; ++hh) {
            const int cb = hh * 128 + lane16 * 8;
            const bfrag hn = *(const bfrag*)(hin + (size_t)node * 256 + cb);
            bfrag o;
            #pragma unroll
            for (int k = 0; k < 8; ++k)
                o[k] = (bf16_t)(eps1 * (float)hn[k] + acc[hh][k]);
            const int j = hh * 16 + lane16;        // seg 0..31
            const int q = j ^ (nidx & 7);          // swizzled position
            *(bfrag*)(xbuf + nidx * 256 + q * 8) = o;
        }
    } else {
        // vn blocks: stage Xv -> xbuf via pre-swizzled global_load_lds (R6 pattern)
        #pragma unroll
        for (int r = 0; r < 2; ++r) {
            const int row = wave * 4 + r * 2 + (lane >> 5);
            const int p   = lane & 31;
            const int j   = p ^ (row & 7);
            const bf16_t* gp = Xv + (rowblk + row) * 256 + j * 8;
            bf16_t* lp = xbuf + (wave * 4 + r * 2) * 256;   // wave-uniform base
            __builtin_amdgcn_global_load_lds(
                (const __attribute__((address_space(1))) void*)gp,
                (__attribute__((address_space(3))) void*)lp, 16, 0, 0);
        }
        asm volatile("s_waitcnt vmcnt(0)" ::: "memory");
    }
    __syncthreads();

    // ---- phase 2: one-shot xa fragment load LDS -> registers ----
    bfrag xa[8][2];
    #pragma unroll
    for (int ks = 0; ks < 8; ++ks) {
        const int seg = (ks * 4 + quad) ^ (c16 & 7);   // (wrow*32+c16)&7 == c16&7
        xa[ks][0] = *(const bfrag*)(xbuf + (wrow * 32 + c16) * 256 + seg * 8);
        xa[ks][1] = *(const bfrag*)(xbuf + (wrow * 32 + 16 + c16) * 256 + seg * 8);
    }
    __syncthreads();   // all xa reads complete before GEMM1 overwrites hid

    // ---- weight staging (R5): units 0..63 W1, 64..127 W2; 8 KB units staged
    // by waves 0-7 only (wave-uniform), source-side XOR, double-buffered ----
    auto stage_unit = [&](int u) {
        if (wave < 8) {
            const int f   = wave * 64 + lane;          // 0..511
            const int col = f >> 2, j = f & 3;
            const bf16_t* gp;
            if (u < 64) {
                const int cps = u >> 3, kc = (u >> 1) & 3, s = u & 1;
                gp = W1T + (size_t)(cps * 128 + col) * 256 + kc * 64 + s * 32
                         + ((j ^ (col & 3)) * 8);
            } else {
                const int u2 = u - 64, cp = u2 >> 5, kk = u2 & 31;
                gp = W2T + (size_t)(cp * 128 + col) * 1024 + kk * 32
                         + ((j ^ (col & 3)) * 8);
            }
            bf16_t* lp = wbuf + (u & 1) * 4096 + wave * 512;   // wave-uniform base
            __builtin_amdgcn_global_load_lds(
                (const __attribute__((address_space(1))) void*)gp,
                (__attribute__((address_space(3))) void*)lp, 16, 0, 0);
        }
    };
    auto wfrag8 = [&](const bf16_t* sb, int crel) -> bfrag {
        return *(const bfrag*)(sb + crel * 32 + ((quad ^ (crel & 3)) * 8));
    };

    // ---- pipeline prologue ----
    stage_unit(0);

    // ---- GEMM1: hid[64,1024] = X[64,256] @ W1 ----
    #pragma unroll
    for (int c = 0; c < 8; ++c) {
        f32x4 acc[2];
        acc[0] = f32x4{0.f, 0.f, 0.f, 0.f};
        acc[1] = f32x4{0.f, 0.f, 0.f, 0.f};
        #pragma unroll
        for (int kc = 0; kc < 4; ++kc) {
            #pragma unroll
            for (int s = 0; s < 2; ++s) {
                const int u = ((c * 4 + kc) << 1) | s;   // 0..63
                lgkm_bar();
                stage_unit(u + 1);                       // u+1 <= 64 (first W2 unit)
                vm_bar<1>();
                const bf16_t* sb = wbuf + (u & 1) * 4096;
                const bfrag w0 = wfrag8(sb, wcol * 16 + c16);
                const int ks = kc * 2 + s;
                acc[0] = __builtin_amdgcn_mfma_f32_16x16x32_bf16(w0, xa[ks][0], acc[0], 0, 0, 0);
                acc[1] = __builtin_amdgcn_mfma_f32_16x16x32_bf16(w0, xa[ks][1], acc[1], 0, 0, 0);
            }
        }
        const int kb = c * 128 + wcol * 16 + quad * 4;
        #pragma unroll
        for (int mt = 0; mt < 2; ++mt) {
            const int xr = wrow * 32 + mt * 16 + c16;
            const f32x4 a = mt ? acc[1] : acc[0];
            b4 o;
            #pragma unroll
            for (int r = 0; r < 4; ++r)
                o[r] = (bf16_t)(a[r] + (float)bias1[c][r]);
            const int ch = ((kb >> 3) ^ (xr & 7));
            *(b4*)(hid + xr * HID + ch * 8 + (kb & 7)) = o;
        }
    }
    lgkm_bar();   // hid visible; W2 unit-64 prefetch stays in flight

    // ---- LN(1024) + GELU in LDS: 16 threads/row, 64 rows ----
    {
        const int row = tid >> 4, p = tid & 15;
        float sum = 0.f, ss = 0.f;
        #pragma unroll
        for (int i = 0; i < HID / 128; ++i) {
            const int j0 = p * 8 + i * 128;
            const int ch = ((j0 >> 3) ^ (row & 7));
            bfrag v = *(const bfrag*)(hid + row * HID + ch * 8);
            #pragma unroll
            for (int k = 0; k < 8; ++k) { const float f = (float)v[k]; sum += f; ss += f * f; }
        }
        #pragma unroll
        for (int o = 1; o < 16; o <<= 1) { sum += __shfl_xor(sum, o, 64); ss += __shfl_xor(ss, o, 64); }
        const float mean = sum * (1.0f / HID);
        const float var  = ss * (1.0f / HID) - mean * mean;
        const float rinv = rsqrtf(var + 1e-5f);
        #pragma unroll
        for (int i = 0; i < HID / 128; ++i) {
            const int j0 = p * 8 + i * 128;
            const int ch = ((j0 >> 3) ^ (row & 7));
            bfrag v  = *(const bfrag*)(hid + row * HID + ch * 8);
            bfrag gv = *(const bfrag*)(lng + j0);
            bfrag bv = *(const bfrag*)(lnb + j0);
            bfrag o8;
            #pragma unroll
            for (int k = 0; k < 8; ++k) {
                const float f = ((float)v[k] - mean) * rinv * (float)gv[k] + (float)bv[k];
                o8[k] = (bf16_t)gelu_f(f);
            }
            *(bfrag*)(hid + row * HID + ch * 8) = o8;
        }
    }
    lgkm_bar();   // LN writes visible; prefetch still in flight

    // ---- GEMM2: res[64,256] = hid[64,1024] @ W2 ----
    {
        f32x4 acc2[2][2];   // [colpass][mt]
        #pragma unroll
        for (int cp = 0; cp < 2; ++cp)
            #pragma unroll
            for (int mt = 0; mt < 2; ++mt)
                acc2[cp][mt] = f32x4{0.f, 0.f, 0.f, 0.f};
        #pragma unroll
        for (int cp = 0; cp < 2; ++cp) {
            #pragma unroll
            for (int kk = 0; kk < 32; ++kk) {
                const int u = 64 + cp * 32 + kk;   // 64..127
                lgkm_bar();
                if (u < 127) { stage_unit(u + 1); vm_bar<1>(); }
                else         { vm_bar<0>(); }
                const bf16_t* sb = wbuf + (u & 1) * 4096;
                const bfrag w0 = wfrag8(sb, wcol * 16 + c16);
                const int k = kk * 32 + quad * 8;
                bfrag hb[2];
                #pragma unroll
                for (int mt = 0; mt < 2; ++mt) {
                    const int row = wrow * 32 + mt * 16 + c16;
                    const int ch = ((k >> 3) ^ (row & 7));
                    hb[mt] = *(const bfrag*)(hid + row * HID + ch * 8);
                }
                acc2[cp][0] = __builtin_amdgcn_mfma_f32_16x16x32_bf16(w0, hb[0], acc2[cp][0], 0, 0, 0);
                acc2[cp][1] = __builtin_amdgcn_mfma_f32_16x16x32_bf16(w0, hb[1], acc2[cp][1], 0, 0, 0);
            }
        }

        if (!is_node) {
            if (has_vn) {
                #pragma unroll
                for (int cp = 0; cp < 2; ++cp)
                    #pragma unroll
                    for (int mt = 0; mt < 2; ++mt) {
                        const int cb = cp * 128 + wcol * 16 + quad * 4;
                        float* po = vnacc + (rowblk + wrow * 32 + mt * 16 + c16) * 256 + cb;
                        const f32x4 old = *(const f32x4*)po;
                        f32x4 v;
                        #pragma unroll
                        for (int r = 0; r < 4; ++r) v[r] = old[r] + acc2[cp][mt][r] + (float)bias2[cp][r];
                        *(f32x4*)po = v;
                    }
            }
        } else {
            constexpr int OS = 260;
            float* ot = (float*)hid;   // 64*260*4 = 66.5 KB, fits the 128 KB hid region
            __syncthreads();
            #pragma unroll
            for (int cp = 0; cp < 2; ++cp)
                #pragma unroll
                for (int mt = 0; mt < 2; ++mt) {
                    const int cb = cp * 128 + wcol * 16 + quad * 4;
                    f32x4 v;
                    #pragma unroll
                    for (int r = 0; r < 4; ++r) v[r] = acc2[cp][mt][r] + (float)bias2[cp][r];
                    *(f32x4*)(ot + (wrow * 32 + mt * 16 + c16) * OS + cb) = v;
                }
            __syncthreads();
            const int row = tid >> 4, p = tid & 15;
            float s = 0.f, q = 0.f;
            #pragma unroll
            for (int i = 0; i < 16; ++i) {
                const float f = ot[row * OS + p + 16 * i];
                s += f; q += f * f;
            }
            #pragma unroll
            for (int o = 1; o < 16; o <<= 1) { s += __shfl_xor(s, o, 64); q += __shfl_xor(q, o, 64); }
            const float mean = s * (1.0f / 256.0f);
            const float var  = q * (1.0f / 256.0f) - mean * mean;
            const float rinv = rsqrtf(var + 1e-5f);
            const size_t rg = (rowblk + row) * 256;
            #pragma unroll
            for (int i = 0; i < 2; ++i) {
                const int j0 = p * 16 + i * 8;
                bfrag gv = *(const bfrag*)(g2 + j0);
                bfrag bv = *(const bfrag*)(b2ln + j0);
                bfrag hv = *(const bfrag*)(hin + rg + j0);   // residual from READ buffer
                bfrag o8;
                #pragma unroll
                for (int k = 0; k < 8; ++k) {
                    float f = (ot[row * OS + j0 + k] - mean) * rinv * (float)gv[k] + (float)bv[k];
                    if (gelu_flag) f = gelu_f(f);
                    o8[k] = (bf16_t)(f + (float)hv[k]);
                }
                *(bfrag*)(hout + rg + j0) = o8;              // write to WRITE buffer
            }
        }
    }
}

// ---------------- small MLP (final projection, HID=256) ----------------
__launch_bounds__(512, 4)
__global__ void k_mlp_proj(const bf16_t* __restrict__ X, const bf16_t* __restrict__ W1T,
                           const bf16_t* __restrict__ b1, const bf16_t* __restrict__ lng,
                           const bf16_t* __restrict__ lnb, const bf16_t* __restrict__ W2T,
                           const bf16_t* __restrict__ b2, float* __restrict__ outf) {
    constexpr int HID = 256;
    constexpr int NP1 = HID / 128;   // 2
    constexpr int NQ2 = HID / 64;    // 4
    __shared__ bf16_t hid[32 * HID];
    __shared__ bf16_t wbuf[8192];
    const int tid  = threadIdx.x;
    const int lane = tid & 63, wave = tid >> 6;
    const int c16  = lane & 15, quad = lane >> 4;
    const size_t rowblk = (size_t)blockIdx.x * 32;

    auto stage = [&](const bf16_t* WT, int KW, int colbase, int k0) {
        #pragma unroll
        for (int j = 0; j < 2; ++j) {
            const int grp    = wave * 2 + j;
            const int colrel = grp * 8 + (lane >> 3);
            const int slot   = lane & 7;
            const int kq     = slot ^ (colrel & 7);
            const bf16_t* gp = WT + (size_t)(colbase + colrel) * KW + k0 + kq * 8;
            bf16_t* lp = &wbuf[(size_t)grp * 512];
            __builtin_amdgcn_global_load_lds(
                (const __attribute__((address_space(1))) void*)gp,
                (__attribute__((address_space(3))) void*)lp, 16, 0, 0);
        }
    };
    auto wfrag = [&](int crel, int g) -> bfrag {
        return *(const bfrag*)(wbuf + crel * 64 + ((g ^ (crel & 7)) * 8));
    };

    const bf16_t* xr0 = X + (rowblk + c16) * 256 + quad * 8;
    const bf16_t* xr1 = X + (rowblk + 16 + c16) * 256 + quad * 8;
    bfrag xa[8][2];
    #pragma unroll
    for (int ks = 0; ks < 8; ++ks) {
        xa[ks][0] = *(const bfrag*)(xr0 + ks * 32);
        xa[ks][1] = *(const bfrag*)(xr1 + ks * 32);
    }

    #pragma unroll
    for (int c = 0; c < NP1; ++c) {
        const int nbase = c * 128 + wave * 16;
        f32x4 acc[2];
        acc[0] = f32x4{0.f, 0.f, 0.f, 0.f};
        acc[1] = f32x4{0.f, 0.f, 0.f, 0.f};
        #pragma unroll
        for (int kc = 0; kc < 4; ++kc) {
            stage(W1T, 256, c * 128, kc * 64);
            __syncthreads();
            #pragma unroll
            for (int s = 0; s < 2; ++s) {
                const int ks = kc * 2 + s;
                const int g  = s * 4 + quad;
                const bfrag w0 = wfrag(wave * 16 + c16, g);
                #pragma unroll
                for (int mt = 0; mt < 2; ++mt)
                    acc[mt] = __builtin_amdgcn_mfma_f32_16x16x32_bf16(
                        w0, xa[ks][mt], acc[mt], 0, 0, 0);
            }
            __syncthreads();
        }
        #pragma unroll
        for (int mt = 0; mt < 2; ++mt) {
            const int kb = nbase + quad * 4;
            const int xr = mt * 16 + c16;
            const b4 bias = *(const b4*)(b1 + kb);
            b4 o;
            #pragma unroll
            for (int r = 0; r < 4; ++r)
                o[r] = (bf16_t)(acc[mt][r] + (float)bias[r]);
            const int ch = ((kb >> 3) ^ (xr & 7));
            *(b4*)(hid + xr * HID + ch * 8 + (kb & 7)) = o;
        }
    }
    __syncthreads();

    {
        const int row = tid >> 4, p = tid & 15;
        float sum = 0.f, ss = 0.f;
        #pragma unroll
        for (int i = 0; i < HID / 128; ++i) {
            const int j0 = p * 8 + i * 128;
            const int ch = ((j0 >> 3) ^ (row & 7));
            bfrag v = *(const bfrag*)(hid + row * HID + ch * 8);
            #pragma unroll
            for (int k = 0; k < 8; ++k) { const float f = (float)v[k]; sum += f; ss += f * f; }
        }
        #pragma unroll
        for (int o = 1; o < 16; o <<= 1) { sum += __shfl_xor(sum, o, 64); ss += __shfl_xor(ss, o, 64); }
        const float mean = sum * (1.0f / HID);
        const float var  = ss * (1.0f / HID) - mean * mean;
        const float rinv = rsqrtf(var + 1e-5f);
        #pragma unroll
        for (int i = 0; i < HID / 128; ++i) {
            const int j0 = p * 8 + i * 128;
            const int ch = ((j0 >> 3) ^ (row & 7));
            bfrag v  = *(const bfrag*)(hid + row * HID + ch * 8);
            bfrag gv = *(const bfrag*)(lng + j0);
            bfrag bv = *(const bfrag*)(lnb + j0);
            bfrag o8;
            #pragma unroll
            for (int k = 0; k < 8; ++k) {
                const float f = ((float)v[k] - mean) * rinv * (float)gv[k] + (float)bv[k];
                o8[k] = (bf16_t)gelu_f(f);
            }
            *(bfrag*)(hid + row * HID + ch * 8) = o8;
        }
    }
    __syncthreads();

    {
        f32x4 acc2[2][2];
        #pragma unroll
        for (int cp = 0; cp < 2; ++cp)
            #pragma unroll
            for (int mt = 0; mt < 2; ++mt)
                acc2[cp][mt] = f32x4{0.f, 0.f, 0.f, 0.f};
        #pragma unroll
        for (int cp = 0; cp < 2; ++cp) {
            for (int q2 = 0; q2 < NQ2; ++q2) {
                stage(W2T, HID, cp * 128, q2 * 64);
                __syncthreads();
                #pragma unroll
                for (int s = 0; s < 2; ++s) {
                    const int g = s * 4 + quad;
                    const bfrag w0 = wfrag(wave * 16 + c16, g);
                    const int k = q2 * 64 + s * 32 + quad * 8;
                    bfrag hb[2];
                    #pragma unroll
                    for (int mt = 0; mt < 2; ++mt) {
                        const int row = mt * 16 + c16;
                        const int ch = ((k >> 3) ^ (row & 7));
                        hb[mt] = *(const bfrag*)(hid + row * HID + ch * 8);
                    }
                    #pragma unroll
                    for (int mt = 0; mt < 2; ++mt)
                        acc2[cp][mt] = __builtin_amdgcn_mfma_f32_16x16x32_bf16(
                            w0, hb[mt], acc2[cp][mt], 0, 0, 0);
                }
                __syncthreads();
            }
        }
        #pragma unroll
        for (int cp = 0; cp < 2; ++cp)
            #pragma unroll
            for (int mt = 0; mt < 2; ++mt) {
                const int cb = cp * 128 + wave * 16 + quad * 4;
                const b4 b2vv = *(const b4*)(b2 + cb);
                f32x4 v;
                #pragma unroll
                for (int r = 0; r < 4; ++r) v[r] = acc2[cp][mt][r] + (float)b2vv[r];
                *(f32x4*)(outf + (rowblk + mt * 16 + c16) * 256 + cb) = v;
            }
    }
}

// ---------------- host launch ----------------
extern "C" void kernel_launch(void* const* d_in, const int* in_sizes, int n_in,
                              void* d_out, int out_size, void* d_ws, size_t ws_size,
                              hipStream_t stream) {
    float* outz = (float*)d_out;

    const bool layout_ok =
        (n_in == 28) &&
        in_sizes[0] == 200000 && in_sizes[1] == 800000 &&
        in_sizes[2] == 400000 && in_sizes[3] == 200000 &&
        in_sizes[4] == 118 * 256 && in_sizes[6] == 5 * 5 * 256 &&
        in_sizes[8] == 5 * 256 * 1024 && in_sizes[27] == 256 &&
        out_size == GG * H;
    if (!layout_ok) {
        k_fill<<<(out_size + 255) / 256, 256, 0, stream>>>(outz, 777.0f, out_size);
        return;
    }

    char* w = (char*)d_ws;
    size_t off = 0;
    auto alloc = [&](size_t bytes) -> void* {
        void* p = w + off;
        off += (bytes + 255) & ~(size_t)255;
        return p;
    };
    bf16_t* hA    = (bf16_t*)alloc((size_t)NN * H * 2);
    bf16_t* hB    = (bf16_t*)alloc((size_t)NN * H * 2);   // ping-pong partner
    float*  vn    = (float*) alloc((size_t)GG * H * 4);
    bf16_t* vpb   = (bf16_t*)alloc((size_t)GG * H * 2);
    bf16_t* hgb   = (bf16_t*)alloc((size_t)GG * H * 2);
    float*  pout2 = (float*) alloc((size_t)GG * H * 4);
    int*    cnt   = (int*)   alloc((size_t)NN * 4);
    int*    slots = (int*)   alloc((size_t)NN * CAP * 4);
    int*    dflag = (int*)   alloc(256);
    bf16_t* cw1T  = (bf16_t*)alloc((size_t)LY * 1024 * 256 * 2);
    bf16_t* cw2T  = (bf16_t*)alloc((size_t)LY * 256 * 1024 * 2);
    bf16_t* vw1T  = (bf16_t*)alloc((size_t)(LY - 1) * 1024 * 256 * 2);
    bf16_t* vw2T  = (bf16_t*)alloc((size_t)(LY - 1) * 256 * 1024 * 2);
    bf16_t* pw1T  = (bf16_t*)alloc((size_t)256 * 256 * 2);
    bf16_t* pw2T  = (bf16_t*)alloc((size_t)256 * 256 * 2);
    bf16_t* atomA = (bf16_t*)alloc((size_t)118 * 256 * 2);
    bf16_t* vneA  = (bf16_t*)alloc(256 * 2);
    bf16_t* bondA = (bf16_t*)alloc((size_t)LY * 5 * 256 * 2);
    bf16_t* epsA  = (bf16_t*)alloc(16 * 2);
    bf16_t* cb1A  = (bf16_t*)alloc((size_t)LY * 1024 * 2);
    bf16_t* clngA = (bf16_t*)alloc((size_t)LY * 1024 * 2);
    bf16_t* clnbA = (bf16_t*)alloc((size_t)LY * 1024 * 2);
    bf16_t* cb2A  = (bf16_t*)alloc((size_t)LY * 256 * 2);
    bf16_t* ngA   = (bf16_t*)alloc((size_t)LY * 256 * 2);
    bf16_t* nbA   = (bf16_t*)alloc((size_t)LY * 256 * 2);
    bf16_t* vb1A  = (bf16_t*)alloc((size_t)(LY - 1) * 1024 * 2);
    bf16_t* vlngA = (bf16_t*)alloc((size_t)(LY - 1) * 1024 * 2);
    bf16_t* vlnbA = (bf16_t*)alloc((size_t)(LY - 1) * 1024 * 2);
    bf16_t* vb2A  = (bf16_t*)alloc((size_t)(LY - 1) * 256 * 2);
    bf16_t* pb1A  = (bf16_t*)alloc(256 * 2);
    bf16_t* plngA = (bf16_t*)alloc(256 * 2);
    bf16_t* plnbA = (bf16_t*)alloc(256 * 2);
    bf16_t* pb2A  = (bf16_t*)alloc(256 * 2);
    if (off > ws_size) {
        k_fill<<<(out_size + 255) / 256, 256, 0, stream>>>(outz, 333.0f, out_size);
        return;
    }

    const int* xi  = (const int*)d_in[0];
    const int* ei  = (const int*)d_in[1];
    const int* ea  = (const int*)d_in[2];

    k_detect<<<1, 64, 0, stream>>>(d_in[8], dflag);

    {
        CvtJobs J{};
        struct { int idx; bf16_t* dst; int n; } cj[18] = {
            {4, atomA, 118 * 256}, {5, vneA, 256}, {6, bondA, LY * 5 * 256}, {7, epsA, LY},
            {9, cb1A, LY * 1024}, {10, clngA, LY * 1024}, {11, clnbA, LY * 1024},
            {13, cb2A, LY * 256}, {14, ngA, LY * 256}, {15, nbA, LY * 256},
            {17, vb1A, (LY - 1) * 1024}, {18, vlngA, (LY - 1) * 1024},
            {19, vlnbA, (LY - 1) * 1024}, {21, vb2A, (LY - 1) * 256},
            {23, pb1A, 256}, {24, plngA, 256}, {25, plnbA, 256}, {27, pb2A, 256},
        };
        int acc = 0;
        J.njobs = 18;
        for (int j = 0; j < 18; ++j) {
            J.src[j] = d_in[cj[j].idx];
            J.dst[j] = cj[j].dst;
            J.pfx[j] = acc;
            acc += cj[j].n;
        }
        J.pfx[18] = acc;
        k_cvt_all<<<(acc + 255) / 256, 256, 0, stream>>>(J, dflag);
    }

    {
        TpJobs J{};
        int nj = 0, acc = 0;
        auto add = [&](int idx, size_t eoff, bf16_t* dst, int R, int C) {
            J.s32[nj] = (const void*)((const float*) d_in[idx] + eoff);
            J.s16[nj] = (const void*)((const bf16_t*)d_in[idx] + eoff);
            J.dst[nj] = dst; J.R[nj] = R; J.C[nj] = C;
            J.pfx[nj] = acc;
            acc += (C / 32) * (R / 32);
            ++nj;
        };
        for (int l = 0; l < LY; ++l) {
            add(8,  (size_t)l * 256 * 1024, cw1T + (size_t)l * 1024 * 256, 256, 1024);
            add(12, (size_t)l * 1024 * 256, cw2T + (size_t)l * 256 * 1024, 1024, 256);
        }
        for (int l = 0; l < LY - 1; ++l) {
            add(16, (size_t)l * 256 * 1024, vw1T + (size_t)l * 1024 * 256, 256, 1024);
            add(20, (size_t)l * 1024 * 256, vw2T + (size_t)l * 256 * 1024, 1024, 256);
        }
        add(22, 0, pw1T, 256, 256);
        add(26, 0, pw2T, 256, 256);
        J.pfx[nj] = acc;
        J.njobs = nj;
        k_tp_all<<<acc, 256, 0, stream>>>(J, dflag);
    }

    k_init_h<<<NN, 256, 0, stream>>>(xi, atomA, hA);
    k_init_vn<<<GG, 256, 0, stream>>>(vneA, vn);
    k_zero_cnt<<<(NN + 255) / 256, 256, 0, stream>>>(cnt);
    k_bucket<<<(EE + 255) / 256, 256, 0, stream>>>(ei, ea, cnt, slots);

    bf16_t* cur = hA;
    bf16_t* nxt = hB;
    for (int l = 0; l < LY; ++l) {
        const int has_vn = (l < LY - 1) ? 1 : 0;
        k_addvn_segmax<<<GG, 128, 0, stream>>>(cur, vn, vpb, has_vn);
        const int lv = (l < LY - 1) ? l : 0;
        k_mlp_dual<<<NBLK_NODE + (has_vn ? NBLK_VN : 0), 1024, 0, stream>>>(
            cur, vpb,
            cnt, slots, bondA + (size_t)l * 5 * H, epsA, l,
            cw1T + (size_t)l * 1024 * 256, vw1T + (size_t)lv * 1024 * 256,
            cb1A + (size_t)l * 1024,       vb1A + (size_t)lv * 1024,
            clngA + (size_t)l * 1024,      vlngA + (size_t)lv * 1024,
            clnbA + (size_t)l * 1024,      vlnbA + (size_t)lv * 1024,
            cw2T + (size_t)l * 256 * 1024, vw2T + (size_t)lv * 256 * 1024,
            cb2A + (size_t)l * 256,        vb2A + (size_t)lv * 256,
            ngA + (size_t)l * H, nbA + (size_t)l * H,
            nxt, vn, has_vn, NBLK_NODE, has_vn);
        bf16_t* t = cur; cur = nxt; nxt = t;
    }

    k_graphsum<<<GG, 128, 0, stream>>>(cur, hgb);
    k_mlp_proj<<<GG / 32, 512, 0, stream>>>(hgb, pw1T, pb1A, plngA, plnbA, pw2T, pb2A, pout2);
    k_norm<<<GG, 256, 0, stream>>>(pout2, outz);
}

// Round 11
// 3840.740 us; speedup vs baseline: 1.3474x; 1.3474x over previous
//
#include <hip/hip_runtime.h>
#include <math.h>

typedef __bf16 bf16_t;
typedef __bf16 bfrag  __attribute__((ext_vector_type(8)));  // 8 bf16 (MFMA A/B frag)
typedef __bf16 b4     __attribute__((ext_vector_type(4)));  // 4 bf16 = 8B vector store
typedef __bf16 b2v    __attribute__((ext_vector_type(2)));  // 2 bf16 = 4B vector
typedef float  f32x4  __attribute__((ext_vector_type(4)));  // MFMA C/D frag

static constexpr int LY  = 5;
static constexpr int H   = 256;
static constexpr int NN  = 200000;
static constexpr int EE  = 400000;
static constexpr int GG  = 8000;
static constexpr int NPG = 25;
static constexpr int CAP = 24;   // max buffered in-edges/node (Poisson(2): P(>24) ~ 1e-17)
static constexpr int NBLK_NODE = NN / 32;   // 6250
static constexpr int NBLK_VN   = GG / 32;   // 250

// tanh-approx GELU (~8 VALU ops; |delta| vs exact erf-gelu ~3e-4 absolute)
__device__ __forceinline__ float gelu_f(float x) {
    const float y = 0.7978845608028654f * x * (1.0f + 0.044715f * x * x);
    const float e = __expf(2.0f * y);
    const float t = 1.0f - 2.0f / (e + 1.0f);
    return 0.5f * x * (1.0f + t);
}

// ---- pipeline sync helpers ----
// unit_bar: the ONLY barrier per unit. lgkmcnt(0) first so every wave's
// ds_reads of the buffer about to be overwritten are drained; the barrier
// then fences the block-wide WAR. No vm drain — prefetches stay in flight.
__device__ __forceinline__ void unit_bar() {
    asm volatile("s_waitcnt lgkmcnt(0)" ::: "memory");
    __builtin_amdgcn_sched_barrier(0);
    __builtin_amdgcn_s_barrier();
    __builtin_amdgcn_sched_barrier(0);
}
// wait_vmN: per-wave counted wait, NO barrier. Valid because each wave's
// MFMA consumes ONLY the 1 KB unit-slice that the same wave staged
// (stage_unit: wave w writes bytes [w*1024, w*1024+1024); wfrag8 reads
// crel in [wave*16, wave*16+16) -> the same bytes).
__device__ __forceinline__ void wait_vm1() {
    asm volatile("s_waitcnt vmcnt(1)" ::: "memory");
    __builtin_amdgcn_sched_barrier(0);
}
__device__ __forceinline__ void wait_vm0() {
    asm volatile("s_waitcnt vmcnt(0)" ::: "memory");
    __builtin_amdgcn_sched_barrier(0);
}

// ---------------- diagnostics ----------------
__global__ void k_fill(float* __restrict__ out, float v, int n) {
    const int i = blockIdx.x * 256 + threadIdx.x;
    if (i < n) out[i] = v;
}

// ---------------- dtype detection ----------------
__global__ void k_detect(const void* __restrict__ probe, int* __restrict__ flag) {
    const bf16_t* p = (const bf16_t*)probe;
    int bad = 0;
    for (int i = threadIdx.x; i < 256; i += 64) {
        const float v = (float)p[i];
        if (!(v == v) || fabsf(v) > 1000.0f) bad = 1;
    }
    const int any = __any(bad) ? 1 : 0;
    if (threadIdx.x == 0) *flag = any;
}

// ---------------- batched param conversion (1 launch) ----------------
struct CvtJobs {
    const void* src[18];
    bf16_t*     dst[18];
    int         pfx[19];
    int         njobs;
};
__global__ void k_cvt_all(CvtJobs J, const int* __restrict__ flag) {
    const int i = blockIdx.x * 256 + threadIdx.x;
    if (i >= J.pfx[J.njobs]) return;
    int j = 0;
    while (i >= J.pfx[j + 1]) ++j;
    const int loc = i - J.pfx[j];
    if (*flag) J.dst[j][loc] = (bf16_t)((const float*)J.src[j])[loc];
    else       J.dst[j][loc] = ((const bf16_t*)J.src[j])[loc];
}

// ---------------- batched weight transpose (1 launch) ----------------
struct TpJobs {
    const void* s32[22];
    const void* s16[22];
    bf16_t*     dst[22];
    int R[22], C[22];
    int pfx[23];
    int njobs;
};
__global__ void k_tp_all(TpJobs J, const int* __restrict__ flag) {
    __shared__ bf16_t t[32][33];
    const int tile = blockIdx.x;
    int j = 0;
    while (tile >= J.pfx[j + 1]) ++j;
    const int tl = tile - J.pfx[j];
    const int C = J.C[j], R = J.R[j];
    const int ntx = C / 32;
    const int c0 = (tl % ntx) * 32, r0 = (tl / ntx) * 32;
    const int f = *flag;
    const int tx = threadIdx.x & 31, ty = threadIdx.x >> 5;
    #pragma unroll
    for (int i = 0; i < 4; ++i) {
        const int r = ty + i * 8;
        const size_t idx = (size_t)(r0 + r) * C + c0 + tx;
        t[r][tx] = f ? (bf16_t)((const float*)J.s32[j])[idx] : ((const bf16_t*)J.s16[j])[idx];
    }
    __syncthreads();
    #pragma unroll
    for (int i = 0; i < 4; ++i) {
        const int r = ty + i * 8;
        J.dst[j][(size_t)(c0 + r) * R + r0 + tx] = t[tx][r];
    }
}

// ---------------- init ----------------
__global__ void k_init_h(const int* __restrict__ x, const bf16_t* __restrict__ atom,
                         bf16_t* __restrict__ h) {
    const size_t idx = (size_t)blockIdx.x * 256 + threadIdx.x;
    const int row = (int)(idx >> 8), col = (int)(idx & 255);
    h[idx] = atom[(size_t)x[row] * H + col];
}

__global__ void k_init_vn(const bf16_t* __restrict__ vne, float* __restrict__ vn) {
    const size_t idx = (size_t)blockIdx.x * 256 + threadIdx.x;
    vn[idx] = (float)vne[idx & 255];
}

// ---------------- edge bucket build (packed src|attr slots) ----------------
__global__ void k_zero_cnt(int* __restrict__ cnt) {
    const int i = blockIdx.x * 256 + threadIdx.x;
    if (i < NN) cnt[i] = 0;
}

// slots hold src | (attr << 18)  (src < 2^18 since NN=200000 < 262144; attr < 8)
__global__ void k_bucket(const int* __restrict__ ei, const int* __restrict__ ea,
                         int* __restrict__ cnt, int* __restrict__ slots) {
    const int e = blockIdx.x * 256 + threadIdx.x;
    if (e >= EE) return;
    const int d = ei[EE + e];
    const int s = ei[e];
    const int a = ea[e];
    const int slot = atomicAdd(&cnt[d], 1);
    if (slot < CAP) slots[(size_t)d * CAP + slot] = s | (a << 18);
}

// ---------------- fused addvn + segment_max (block = 1 graph, bf16x2 lanes) ----------------
__global__ void k_addvn_segmax(bf16_t* __restrict__ h, const float* __restrict__ vn,
                               bf16_t* __restrict__ vp, int do_max) {
    const int g = blockIdx.x, t = threadIdx.x;   // 128 threads; cols 2t, 2t+1
    const float2 v = *(const float2*)(vn + (size_t)g * H + 2 * t);
    float mx0 = -1e30f, mx1 = -1e30f;
    #pragma unroll 5
    for (int i = 0; i < NPG; ++i) {
        bf16_t* p = h + ((size_t)g * NPG + i) * H + 2 * t;
        const b2v hv = *(const b2v*)p;
        const float h0 = (float)hv[0] + v.x;
        const float h1 = (float)hv[1] + v.y;
        b2v o; o[0] = (bf16_t)h0; o[1] = (bf16_t)h1;
        *(b2v*)p = o;
        mx0 = fmaxf(mx0, h0); mx1 = fmaxf(mx1, h1);
    }
    if (do_max) {
        b2v o; o[0] = (bf16_t)mx0; o[1] = (bf16_t)mx1;
        *(b2v*)(vp + (size_t)g * H + 2 * t) = o;
    }
}

__global__ void k_graphsum(const bf16_t* __restrict__ h, bf16_t* __restrict__ hg) {
    const int g = blockIdx.x, t = threadIdx.x;   // 128 threads
    float s0 = 0.0f, s1 = 0.0f;
    #pragma unroll 5
    for (int i = 0; i < NPG; ++i) {
        const b2v hv = *(const b2v*)(h + ((size_t)g * NPG + i) * H + 2 * t);
        s0 += (float)hv[0]; s1 += (float)hv[1];
    }
    b2v o; o[0] = (bf16_t)s0; o[1] = (bf16_t)s1;
    *(b2v*)(hg + (size_t)g * H + 2 * t) = o;
}

__global__ void k_norm(const float* __restrict__ z, float* __restrict__ out) {
    const int row = blockIdx.x, t = threadIdx.x;
    const size_t idx = (size_t)row * H + t;
    const float v = z[idx];
    float q = v * v;
    #pragma unroll
    for (int o = 32; o > 0; o >>= 1) q += __shfl_xor(q, o, 64);
    __shared__ float rq[4];
    const int wave = t >> 6, lane = t & 63;
    if (lane == 0) rq[wave] = q;
    __syncthreads();
    q = rq[0] + rq[1] + rq[2] + rq[3];
    out[idx] = v * rsqrtf(q);
}

// ---------------- fused GATHER + MLP dual (R9 core, single-barrier units + prologue overlap) ----------------
// Identical to R9 (cooperative LDS gather aliasing hid's first 16 KB, one-shot
// xa load, 2 x 8 KB counted-vmcnt weight units, 80 KB LDS, 2 blk/CU) with two
// overhead cuts:
//  (1) ONE barrier per unit instead of two. The unit's data flow is per-wave
//      private (wave w stages bytes [w*1024,w*1024+1024) and reads exactly
//      those), so the vm wait needs no barrier; only the WAR fence does:
//      {lgkmcnt(0); s_barrier; stage(u+1); vmcnt(1); compute(u)}.
//  (2) stage(0) AND stage(1) are issued BEFORE the gather phase — both 8 KB
//      prefetches land for free under the ~100 us gather (in-order vmcnt
//      retirement keeps all implicit waits strictly correct).
__launch_bounds__(512, 4)
__global__ void k_mlp_dual(const bf16_t* __restrict__ hin, const bf16_t* __restrict__ Xv,
                           const int* __restrict__ cnt, const int* __restrict__ slots,
                           const bf16_t* __restrict__ bondl, const bf16_t* __restrict__ epsb, int lidx,
                           const bf16_t* __restrict__ nW1T, const bf16_t* __restrict__ vW1T,
                           const bf16_t* __restrict__ nb1, const bf16_t* __restrict__ vb1,
                           const bf16_t* __restrict__ nlng, const bf16_t* __restrict__ vlng,
                           const bf16_t* __restrict__ nlnb, const bf16_t* __restrict__ vlnb,
                           const bf16_t* __restrict__ nW2T, const bf16_t* __restrict__ vW2T,
                           const bf16_t* __restrict__ nb2, const bf16_t* __restrict__ vb2,
                           const bf16_t* __restrict__ g2, const bf16_t* __restrict__ b2ln,
                           bf16_t* __restrict__ hout, float* __restrict__ vnacc,
                           int gelu_flag, int nblk_node, int has_vn) {
    constexpr int HID = 1024;
    __shared__ __align__(16) bf16_t hid[32 * HID];  // 64 KB (first 16 KB doubles as X-tile)
    __shared__ __align__(16) bf16_t wbuf[8192];     // 16 KB = 2 x 8 KB units
    bf16_t* xbuf = hid;                             // X-tile alias: 32 rows x 256 (swizzled)
    const int tid  = threadIdx.x;
    const int lane = tid & 63, wave = tid >> 6;
    const int c16  = lane & 15, quad = lane >> 4;

    const bool is_node = (int)blockIdx.x < nblk_node;
    const size_t rowblk = is_node ? (size_t)blockIdx.x * 32
                                  : (size_t)((int)blockIdx.x - nblk_node) * 32;
    const bf16_t* W1T  = is_node ? nW1T : vW1T;
    const bf16_t* W2T  = is_node ? nW2T : vW2T;
    const bf16_t* b1   = is_node ? nb1  : vb1;
    const bf16_t* lng  = is_node ? nlng : vlng;
    const bf16_t* lnb  = is_node ? nlnb : vlnb;
    const bf16_t* b2   = is_node ? nb2  : vb2;

    // units 0..63: W1 (c=u>>3, kc=(u>>1)&3, s=u&1); 64..127: W2 (cp, kk).
    // unit = 128 cols x 32 k = 8 KB; 512 threads x 16 B; slot f: col=f>>2, j=f&3.
    // content at (col,j) = W[col][k0 + (j^(col&3))*8]  (source-side XOR).
    auto stage_unit = [&](int u) {
        const int f   = wave * 64 + lane;          // 0..511
        const int col = f >> 2, j = f & 3;
        const bf16_t* gp;
        if (u < 64) {
            const int cps = u >> 3, kc = (u >> 1) & 3, s = u & 1;
            gp = W1T + (size_t)(cps * 128 + col) * 256 + kc * 64 + s * 32
                     + ((j ^ (col & 3)) * 8);
        } else {
            const int u2 = u - 64, cp = u2 >> 5, kk = u2 & 31;
            gp = W2T + (size_t)(cp * 128 + col) * 1024 + kk * 32
                     + ((j ^ (col & 3)) * 8);
        }
        bf16_t* lp = wbuf + (u & 1) * 4096 + wave * 512;   // wave-uniform base
        __builtin_amdgcn_global_load_lds(
            (const __attribute__((address_space(1))) void*)gp,
            (__attribute__((address_space(3))) void*)lp, 16, 0, 0);
    };
    auto wfrag8 = [&](const bf16_t* sb, int crel) -> bfrag {
        return *(const bfrag*)(sb + crel * 32 + ((quad ^ (crel & 3)) * 8));
    };

    // ---- bias preload (R5 discipline: no stray global loads in GEMM loops) ----
    b4 bias1[8], bias2[2];
    #pragma unroll
    for (int c = 0; c < 8; ++c)
        bias1[c] = *(const b4*)(b1 + c * 128 + wave * 16 + quad * 4);
    #pragma unroll
    for (int cp = 0; cp < 2; ++cp)
        bias2[cp] = *(const b4*)(b2 + cp * 128 + wave * 16 + quad * 4);

    // ---- prologue prefetch: both weight buffers land under the gather ----
    stage_unit(0);
    stage_unit(1);

    // ---- phase 1: build X-tile in LDS (swizzled: row r, 16B-seg j stored at
    // position j ^ (r&7)) ----
    if (is_node) {
        // cooperative gather: wave handles 4 nodes; 16 lanes per node.
        const float eps1 = 1.0f + (float)epsb[lidx];
        const int n_sub  = lane >> 4;          // 0..3
        const int lane16 = lane & 15;          // 0..15
        const int nidx   = wave * 4 + n_sub;   // 0..31
        const int node   = (int)rowblk + nidx;
        int deg = cnt[node];
        if (deg > CAP) deg = CAP;
        const int sbase = node * CAP;
        float acc[2][8];
        #pragma unroll
        for (int hh = 0; hh < 2; ++hh)
            #pragma unroll
            for (int k = 0; k < 8; ++k) acc[hh][k] = 0.f;
        for (int i = 0; i < deg; ++i) {
            const int p  = slots[sbase + i];
            const int s  = p & 0x3FFFF;
            const int at = p >> 18;
            #pragma unroll
            for (int hh = 0; hh < 2; ++hh) {
                const int cb = hh * 128 + lane16 * 8;
                const bfrag hv = *(const bfrag*)(hin + (size_t)s * 256 + cb);
                const bfrag bv = *(const bfrag*)(bondl + (size_t)at * 256 + cb);
                #pragma unroll
                for (int k = 0; k < 8; ++k)
                    acc[hh][k] += gelu_f((float)hv[k] + (float)bv[k]);
            }
        }
        #pragma unroll
        for (int hh = 0; hh < 2; ++hh) {
            const int cb = hh * 128 + lane16 * 8;
            const bfrag hn = *(const bfrag*)(hin + (size_t)node * 256 + cb);
            bfrag o;
            #pragma unroll
            for (int k = 0; k < 8; ++k)
                o[k] = (bf16_t)(eps1 * (float)hn[k] + acc[hh][k]);
            const int j = hh * 16 + lane16;        // seg 0..31
            const int q = j ^ (nidx & 7);          // swizzled position
            *(bfrag*)(xbuf + nidx * 256 + q * 8) = o;
        }
    } else {
        // vn blocks: stage Xv -> xbuf via pre-swizzled global_load_lds (R6 pattern)
        #pragma unroll
        for (int r = 0; r < 2; ++r) {
            const int row = r * 16 + wave * 2 + (lane >> 5);
            const int p   = lane & 31;
            const int j   = p ^ (row & 7);
            const bf16_t* gp = Xv + (rowblk + row) * 256 + j * 8;
            bf16_t* lp = xbuf + (r * 16 + wave * 2) * 256;   // wave-uniform base
            __builtin_amdgcn_global_load_lds(
                (const __attribute__((address_space(1))) void*)gp,
                (__attribute__((address_space(3))) void*)lp, 16, 0, 0);
        }
        asm volatile("s_waitcnt vmcnt(0)" ::: "memory");
    }
    __syncthreads();

    // ---- phase 2: one-shot xa fragment load LDS -> registers ----
    bfrag xa[8][2];
    #pragma unroll
    for (int ks = 0; ks < 8; ++ks) {
        const int seg = (ks * 4 + quad) ^ (c16 & 7);
        xa[ks][0] = *(const bfrag*)(xbuf + c16 * 256 + seg * 8);
        xa[ks][1] = *(const bfrag*)(xbuf + (16 + c16) * 256 + seg * 8);
    }
    __syncthreads();   // all xa reads complete before GEMM1 overwrites hid

    // ---- GEMM1: hid[32,1024] = X[32,256] @ W1 ----
    #pragma unroll
    for (int c = 0; c < 8; ++c) {
        f32x4 acc[2];
        acc[0] = f32x4{0.f, 0.f, 0.f, 0.f};
        acc[1] = f32x4{0.f, 0.f, 0.f, 0.f};
        #pragma unroll
        for (int kc = 0; kc < 4; ++kc) {
            #pragma unroll
            for (int s = 0; s < 2; ++s) {
                const int u = ((c * 4 + kc) << 1) | s;   // 0..63
                unit_bar();
                if (u >= 1) stage_unit(u + 1);           // units 2..64 (64 = first W2)
                wait_vm1();
                const bf16_t* sb = wbuf + (u & 1) * 4096;
                const bfrag w0 = wfrag8(sb, wave * 16 + c16);
                const int ks = kc * 2 + s;
                acc[0] = __builtin_amdgcn_mfma_f32_16x16x32_bf16(w0, xa[ks][0], acc[0], 0, 0, 0);
                acc[1] = __builtin_amdgcn_mfma_f32_16x16x32_bf16(w0, xa[ks][1], acc[1], 0, 0, 0);
            }
        }
        const int kb = c * 128 + wave * 16 + quad * 4;
        #pragma unroll
        for (int mt = 0; mt < 2; ++mt) {
            const int xr = mt * 16 + c16;
            const f32x4 a = mt ? acc[1] : acc[0];
            b4 o;
            #pragma unroll
            for (int r = 0; r < 4; ++r)
                o[r] = (bf16_t)(a[r] + (float)bias1[c][r]);
            const int ch = ((kb >> 3) ^ (xr & 7));
            *(b4*)(hid + xr * HID + ch * 8 + (kb & 7)) = o;
        }
    }
    unit_bar();   // hid visible; W2 unit-64 prefetch stays in flight

    // ---- LN(1024) + GELU in LDS: 16 threads/row ----
    {
        const int row = tid >> 4, p = tid & 15;
        float sum = 0.f, ss = 0.f;
        #pragma unroll
        for (int i = 0; i < HID / 128; ++i) {
            const int j0 = p * 8 + i * 128;
            const int ch = ((j0 >> 3) ^ (row & 7));
            bfrag v = *(const bfrag*)(hid + row * HID + ch * 8);
            #pragma unroll
            for (int k = 0; k < 8; ++k) { const float f = (float)v[k]; sum += f; ss += f * f; }
        }
        #pragma unroll
        for (int o = 1; o < 16; o <<= 1) { sum += __shfl_xor(sum, o, 64); ss += __shfl_xor(ss, o, 64); }
        const float mean = sum * (1.0f / HID);
        const float var  = ss * (1.0f / HID) - mean * mean;
        const float rinv = rsqrtf(var + 1e-5f);
        #pragma unroll
        for (int i = 0; i < HID / 128; ++i) {
            const int j0 = p * 8 + i * 128;
            const int ch = ((j0 >> 3) ^ (row & 7));
            bfrag v  = *(const bfrag*)(hid + row * HID + ch * 8);
            bfrag gv = *(const bfrag*)(lng + j0);
            bfrag bv = *(const bfrag*)(lnb + j0);
            bfrag o8;
            #pragma unroll
            for (int k = 0; k < 8; ++k) {
                const float f = ((float)v[k] - mean) * rinv * (float)gv[k] + (float)bv[k];
                o8[k] = (bf16_t)gelu_f(f);
            }
            *(bfrag*)(hid + row * HID + ch * 8) = o8;
        }
    }
    unit_bar();   // LN writes visible; prefetch still in flight

    // ---- GEMM2: res[32,256] = hid[32,1024] @ W2 ----
    {
        f32x4 acc2[2][2];   // [colpass][mt]
        #pragma unroll
        for (int cp = 0; cp < 2; ++cp)
            #pragma unroll
            for (int mt = 0; mt < 2; ++mt)
                acc2[cp][mt] = f32x4{0.f, 0.f, 0.f, 0.f};
        #pragma unroll
        for (int cp = 0; cp < 2; ++cp) {
            #pragma unroll
            for (int kk = 0; kk < 32; ++kk) {
                const int u = 64 + cp * 32 + kk;   // 64..127
                unit_bar();
                if (u < 127) { stage_unit(u + 1); wait_vm1(); }
                else         { wait_vm0(); }
                const bf16_t* sb = wbuf + (u & 1) * 4096;
                const bfrag w0 = wfrag8(sb, wave * 16 + c16);
                const int k = kk * 32 + quad * 8;
                bfrag hb[2];
                #pragma unroll
                for (int mt = 0; mt < 2; ++mt) {
                    const int row = mt * 16 + c16;
                    const int ch = ((k >> 3) ^ (row & 7));
                    hb[mt] = *(const bfrag*)(hid + row * HID + ch * 8);
                }
                acc2[cp][0] = __builtin_amdgcn_mfma_f32_16x16x32_bf16(w0, hb[0], acc2[cp][0], 0, 0, 0);
                acc2[cp][1] = __builtin_amdgcn_mfma_f32_16x16x32_bf16(w0, hb[1], acc2[cp][1], 0, 0, 0);
            }
        }

        if (!is_node) {
            if (has_vn) {
                #pragma unroll
                for (int cp = 0; cp < 2; ++cp)
                    #pragma unroll
                    for (int mt = 0; mt < 2; ++mt) {
                        const int cb = cp * 128 + wave * 16 + quad * 4;
                        float* po = vnacc + (rowblk + mt * 16 + c16) * 256 + cb;
                        const f32x4 old = *(const f32x4*)po;
                        f32x4 v;
                        #pragma unroll
                        for (int r = 0; r < 4; ++r) v[r] = old[r] + acc2[cp][mt][r] + (float)bias2[cp][r];
                        *(f32x4*)po = v;
                    }
            }
        } else {
            constexpr int OS = 260;
            float* ot = (float*)hid;
            __syncthreads();
            #pragma unroll
            for (int cp = 0; cp < 2; ++cp)
                #pragma unroll
                for (int mt = 0; mt < 2; ++mt) {
                    const int cb = cp * 128 + wave * 16 + quad * 4;
                    f32x4 v;
                    #pragma unroll
                    for (int r = 0; r < 4; ++r) v[r] = acc2[cp][mt][r] + (float)bias2[cp][r];
                    *(f32x4*)(ot + (mt * 16 + c16) * OS + cb) = v;
                }
            __syncthreads();
            const int row = tid >> 4, p = tid & 15;
            float s = 0.f, q = 0.f;
            #pragma unroll
            for (int i = 0; i < 16; ++i) {
                const float f = ot[row * OS + p + 16 * i];
                s += f; q += f * f;
            }
            #pragma unroll
            for (int o = 1; o < 16; o <<= 1) { s += __shfl_xor(s, o, 64); q += __shfl_xor(q, o, 64); }
            const float mean = s * (1.0f / 256.0f);
            const float var  = q * (1.0f / 256.0f) - mean * mean;
            const float rinv = rsqrtf(var + 1e-5f);
            const size_t rg = (rowblk + row) * 256;
            #pragma unroll
            for (int i = 0; i < 2; ++i) {
                const int j0 = p * 16 + i * 8;
                bfrag gv = *(const bfrag*)(g2 + j0);
                bfrag bv = *(const bfrag*)(b2ln + j0);
                bfrag hv = *(const bfrag*)(hin + rg + j0);   // residual from READ buffer
                bfrag o8;
                #pragma unroll
                for (int k = 0; k < 8; ++k) {
                    float f = (ot[row * OS + j0 + k] - mean) * rinv * (float)gv[k] + (float)bv[k];
                    if (gelu_flag) f = gelu_f(f);
                    o8[k] = (bf16_t)(f + (float)hv[k]);
                }
                *(bfrag*)(hout + rg + j0) = o8;              // write to WRITE buffer
            }
        }
    }
}

// ---------------- small MLP (final projection, HID=256) ----------------
__launch_bounds__(512, 4)
__global__ void k_mlp_proj(const bf16_t* __restrict__ X, const bf16_t* __restrict__ W1T,
                           const bf16_t* __restrict__ b1, const bf16_t* __restrict__ lng,
                           const bf16_t* __restrict__ lnb, const bf16_t* __restrict__ W2T,
                           const bf16_t* __restrict__ b2, float* __restrict__ outf) {
    constexpr int HID = 256;
    constexpr int NP1 = HID / 128;   // 2
    constexpr int NQ2 = HID / 64;    // 4
    __shared__ bf16_t hid[32 * HID];
    __shared__ bf16_t wbuf[8192];
    const int tid  = threadIdx.x;
    const int lane = tid & 63, wave = tid >> 6;
    const int c16  = lane & 15, quad = lane >> 4;
    const size_t rowblk = (size_t)blockIdx.x * 32;

    auto stage = [&](const bf16_t* WT, int KW, int colbase, int k0) {
        #pragma unroll
        for (int j = 0; j < 2; ++j) {
            const int grp    = wave * 2 + j;
            const int colrel = grp * 8 + (lane >> 3);
            const int slot   = lane & 7;
            const int kq     = slot ^ (colrel & 7);
            const bf16_t* gp = WT + (size_t)(colbase + colrel) * KW + k0 + kq * 8;
            bf16_t* lp = &wbuf[(size_t)grp * 512];
            __builtin_amdgcn_global_load_lds(
                (const __attribute__((address_space(1))) void*)gp,
                (__attribute__((address_space(3))) void*)lp, 16, 0, 0);
        }
    };
    auto wfrag = [&](int crel, int g) -> bfrag {
        return *(const bfrag*)(wbuf + crel * 64 + ((g ^ (crel & 7)) * 8));
    };

    const bf16_t* xr0 = X + (rowblk + c16) * 256 + quad * 8;
    const bf16_t* xr1 = X + (rowblk + 16 + c16) * 256 + quad * 8;
    bfrag xa[8][2];
    #pragma unroll
    for (int ks = 0; ks < 8; ++ks) {
        xa[ks][0] = *(const bfrag*)(xr0 + ks * 32);
        xa[ks][1] = *(const bfrag*)(xr1 + ks * 32);
    }

    #pragma unroll
    for (int c = 0; c < NP1; ++c) {
        const int nbase = c * 128 + wave * 16;
        f32x4 acc[2];
        acc[0] = f32x4{0.f, 0.f, 0.f, 0.f};
        acc[1] = f32x4{0.f, 0.f, 0.f, 0.f};
        #pragma unroll
        for (int kc = 0; kc < 4; ++kc) {
            stage(W1T, 256, c * 128, kc * 64);
            __syncthreads();
            #pragma unroll
            for (int s = 0; s < 2; ++s) {
                const int ks = kc * 2 + s;
                const int g  = s * 4 + quad;
                const bfrag w0 = wfrag(wave * 16 + c16, g);
                #pragma unroll
                for (int mt = 0; mt < 2; ++mt)
                    acc[mt] = __builtin_amdgcn_mfma_f32_16x16x32_bf16(
                        w0, xa[ks][mt], acc[mt], 0, 0, 0);
            }
            __syncthreads();
        }
        #pragma unroll
        for (int mt = 0; mt < 2; ++mt) {
            const int kb = nbase + quad * 4;
            const int xr = mt * 16 + c16;
            const b4 bias = *(const b4*)(b1 + kb);
            b4 o;
            #pragma unroll
            for (int r = 0; r < 4; ++r)
                o[r] = (bf16_t)(acc[mt][r] + (float)bias[r]);
            const int ch = ((kb >> 3) ^ (xr & 7));
            *(b4*)(hid + xr * HID + ch * 8 + (kb & 7)) = o;
        }
    }
    __syncthreads();

    {
        const int row = tid >> 4, p = tid & 15;
        float sum = 0.f, ss = 0.f;
        #pragma unroll
        for (int i = 0; i < HID / 128; ++i) {
            const int j0 = p * 8 + i * 128;
            const int ch = ((j0 >> 3) ^ (row & 7));
            bfrag v = *(const bfrag*)(hid + row * HID + ch * 8);
            #pragma unroll
            for (int k = 0; k < 8; ++k) { const float f = (float)v[k]; sum += f; ss += f * f; }
        }
        #pragma unroll
        for (int o = 1; o < 16; o <<= 1) { sum += __shfl_xor(sum, o, 64); ss += __shfl_xor(ss, o, 64); }
        const float mean = sum * (1.0f / HID);
        const float var  = ss * (1.0f / HID) - mean * mean;
        const float rinv = rsqrtf(var + 1e-5f);
        #pragma unroll
        for (int i = 0; i < HID / 128; ++i) {
            const int j0 = p * 8 + i * 128;
            const int ch = ((j0 >> 3) ^ (row & 7));
            bfrag v  = *(const bfrag*)(hid + row * HID + ch * 8);
            bfrag gv = *(const bfrag*)(lng + j0);
            bfrag bv = *(const bfrag*)(lnb + j0);
            bfrag o8;
            #pragma unroll
            for (int k = 0; k < 8; ++k) {
                const float f = ((float)v[k] - mean) * rinv * (float)gv[k] + (float)bv[k];
                o8[k] = (bf16_t)gelu_f(f);
            }
            *(bfrag*)(hid + row * HID + ch * 8) = o8;
        }
    }
    __syncthreads();

    {
        f32x4 acc2[2][2];
        #pragma unroll
        for (int cp = 0; cp < 2; ++cp)
            #pragma unroll
            for (int mt = 0; mt < 2; ++mt)
                acc2[cp][mt] = f32x4{0.f, 0.f, 0.f, 0.f};
        #pragma unroll
        for (int cp = 0; cp < 2; ++cp) {
            for (int q2 = 0; q2 < NQ2; ++q2) {
                stage(W2T, HID, cp * 128, q2 * 64);
                __syncthreads();
                #pragma unroll
                for (int s = 0; s < 2; ++s) {
                    const int g = s * 4 + quad;
                    const bfrag w0 = wfrag(wave * 16 + c16, g);
                    const int k = q2 * 64 + s * 32 + quad * 8;
                    bfrag hb[2];
                    #pragma unroll
                    for (int mt = 0; mt < 2; ++mt) {
                        const int row = mt * 16 + c16;
                        const int ch = ((k >> 3) ^ (row & 7));
                        hb[mt] = *(const bfrag*)(hid + row * HID + ch * 8);
                    }
                    #pragma unroll
                    for (int mt = 0; mt < 2; ++mt)
                        acc2[cp][mt] = __builtin_amdgcn_mfma_f32_16x16x32_bf16(
                            w0, hb[mt], acc2[cp][mt], 0, 0, 0);
                }
                __syncthreads();
            }
        }
        #pragma unroll
        for (int cp = 0; cp < 2; ++cp)
            #pragma unroll
            for (int mt = 0; mt < 2; ++mt) {
                const int cb = cp * 128 + wave * 16 + quad * 4;
                const b4 b2vv = *(const b4*)(b2 + cb);
                f32x4 v;
                #pragma unroll
                for (int r = 0; r < 4; ++r) v[r] = acc2[cp][mt][r] + (float)b2vv[r];
                *(f32x4*)(outf + (rowblk + mt * 16 + c16) * 256 + cb) = v;
            }
    }
}

// ---------------- host launch ----------------
extern "C" void kernel_launch(void* const* d_in, const int* in_sizes, int n_in,
                              void* d_out, int out_size, void* d_ws, size_t ws_size,
                              hipStream_t stream) {
    float* outz = (float*)d_out;

    const bool layout_ok =
        (n_in == 28) &&
        in_sizes[0] == 200000 && in_sizes[1] == 800000 &&
        in_sizes[2] == 400000 && in_sizes[3] == 200000 &&
        in_sizes[4] == 118 * 256 && in_sizes[6] == 5 * 5 * 256 &&
        in_sizes[8] == 5 * 256 * 1024 && in_sizes[27] == 256 &&
        out_size == GG * H;
    if (!layout_ok) {
        k_fill<<<(out_size + 255) / 256, 256, 0, stream>>>(outz, 777.0f, out_size);
        return;
    }

    char* w = (char*)d_ws;
    size_t off = 0;
    auto alloc = [&](size_t bytes) -> void* {
        void* p = w + off;
        off += (bytes + 255) & ~(size_t)255;
        return p;
    };
    bf16_t* hA    = (bf16_t*)alloc((size_t)NN * H * 2);
    bf16_t* hB    = (bf16_t*)alloc((size_t)NN * H * 2);   // ping-pong partner
    float*  vn    = (float*) alloc((size_t)GG * H * 4);
    bf16_t* vpb   = (bf16_t*)alloc((size_t)GG * H * 2);
    bf16_t* hgb   = (bf16_t*)alloc((size_t)GG * H * 2);
    float*  pout2 = (float*) alloc((size_t)GG * H * 4);
    int*    cnt   = (int*)   alloc((size_t)NN * 4);
    int*    slots = (int*)   alloc((size_t)NN * CAP * 4);
    int*    dflag = (int*)   alloc(256);
    bf16_t* cw1T  = (bf16_t*)alloc((size_t)LY * 1024 * 256 * 2);
    bf16_t* cw2T  = (bf16_t*)alloc((size_t)LY * 256 * 1024 * 2);
    bf16_t* vw1T  = (bf16_t*)alloc((size_t)(LY - 1) * 1024 * 256 * 2);
    bf16_t* vw2T  = (bf16_t*)alloc((size_t)(LY - 1) * 256 * 1024 * 2);
    bf16_t* pw1T  = (bf16_t*)alloc((size_t)256 * 256 * 2);
    bf16_t* pw2T  = (bf16_t*)alloc((size_t)256 * 256 * 2);
    bf16_t* atomA = (bf16_t*)alloc((size_t)118 * 256 * 2);
    bf16_t* vneA  = (bf16_t*)alloc(256 * 2);
    bf16_t* bondA = (bf16_t*)alloc((size_t)LY * 5 * 256 * 2);
    bf16_t* epsA  = (bf16_t*)alloc(16 * 2);
    bf16_t* cb1A  = (bf16_t*)alloc((size_t)LY * 1024 * 2);
    bf16_t* clngA = (bf16_t*)alloc((size_t)LY * 1024 * 2);
    bf16_t* clnbA = (bf16_t*)alloc((size_t)LY * 1024 * 2);
    bf16_t* cb2A  = (bf16_t*)alloc((size_t)LY * 256 * 2);
    bf16_t* ngA   = (bf16_t*)alloc((size_t)LY * 256 * 2);
    bf16_t* nbA   = (bf16_t*)alloc((size_t)LY * 256 * 2);
    bf16_t* vb1A  = (bf16_t*)alloc((size_t)(LY - 1) * 1024 * 2);
    bf16_t* vlngA = (bf16_t*)alloc((size_t)(LY - 1) * 1024 * 2);
    bf16_t* vlnbA = (bf16_t*)alloc((size_t)(LY - 1) * 1024 * 2);
    bf16_t* vb2A  = (bf16_t*)alloc((size_t)(LY - 1) * 256 * 2);
    bf16_t* pb1A  = (bf16_t*)alloc(256 * 2);
    bf16_t* plngA = (bf16_t*)alloc(256 * 2);
    bf16_t* plnbA = (bf16_t*)alloc(256 * 2);
    bf16_t* pb2A  = (bf16_t*)alloc(256 * 2);
    if (off > ws_size) {
        k_fill<<<(out_size + 255) / 256, 256, 0, stream>>>(outz, 333.0f, out_size);
        return;
    }

    const int* xi  = (const int*)d_in[0];
    const int* ei  = (const int*)d_in[1];
    const int* ea  = (const int*)d_in[2];

    k_detect<<<1, 64, 0, stream>>>(d_in[8], dflag);

    {
        CvtJobs J{};
        struct { int idx; bf16_t* dst; int n; } cj[18] = {
            {4, atomA, 118 * 256}, {5, vneA, 256}, {6, bondA, LY * 5 * 256}, {7, epsA, LY},
            {9, cb1A, LY * 1024}, {10, clngA, LY * 1024}, {11, clnbA, LY * 1024},
            {13, cb2A, LY * 256}, {14, ngA, LY * 256}, {15, nbA, LY * 256},
            {17, vb1A, (LY - 1) * 1024}, {18, vlngA, (LY - 1) * 1024},
            {19, vlnbA, (LY - 1) * 1024}, {21, vb2A, (LY - 1) * 256},
            {23, pb1A, 256}, {24, plngA, 256}, {25, plnbA, 256}, {27, pb2A, 256},
        };
        int acc = 0;
        J.njobs = 18;
        for (int j = 0; j < 18; ++j) {
            J.src[j] = d_in[cj[j].idx];
            J.dst[j] = cj[j].dst;
            J.pfx[j] = acc;
            acc += cj[j].n;
        }
        J.pfx[18] = acc;
        k_cvt_all<<<(acc + 255) / 256, 256, 0, stream>>>(J, dflag);
    }

    {
        TpJobs J{};
        int nj = 0, acc = 0;
        auto add = [&](int idx, size_t eoff, bf16_t* dst, int R, int C) {
            J.s32[nj] = (const void*)((const float*) d_in[idx] + eoff);
            J.s16[nj] = (const void*)((const bf16_t*)d_in[idx] + eoff);
            J.dst[nj] = dst; J.R[nj] = R; J.C[nj] = C;
            J.pfx[nj] = acc;
            acc += (C / 32) * (R / 32);
            ++nj;
        };
        for (int l = 0; l < LY; ++l) {
            add(8,  (size_t)l * 256 * 1024, cw1T + (size_t)l * 1024 * 256, 256, 1024);
            add(12, (size_t)l * 1024 * 256, cw2T + (size_t)l * 256 * 1024, 1024, 256);
        }
        for (int l = 0; l < LY - 1; ++l) {
            add(16, (size_t)l * 256 * 1024, vw1T + (size_t)l * 1024 * 256, 256, 1024);
            add(20, (size_t)l * 1024 * 256, vw2T + (size_t)l * 256 * 1024, 1024, 256);
        }
        add(22, 0, pw1T, 256, 256);
        add(26, 0, pw2T, 256, 256);
        J.pfx[nj] = acc;
        J.njobs = nj;
        k_tp_all<<<acc, 256, 0, stream>>>(J, dflag);
    }

    k_init_h<<<NN, 256, 0, stream>>>(xi, atomA, hA);
    k_init_vn<<<GG, 256, 0, stream>>>(vneA, vn);
    k_zero_cnt<<<(NN + 255) / 256, 256, 0, stream>>>(cnt);
    k_bucket<<<(EE + 255) / 256, 256, 0, stream>>>(ei, ea, cnt, slots);

    bf16_t* cur = hA;
    bf16_t* nxt = hB;
    for (int l = 0; l < LY; ++l) {
        const int has_vn = (l < LY - 1) ? 1 : 0;
        k_addvn_segmax<<<GG, 128, 0, stream>>>(cur, vn, vpb, has_vn);
        const int lv = (l < LY - 1) ? l : 0;
        k_mlp_dual<<<NBLK_NODE + (has_vn ? NBLK_VN : 0), 512, 0, stream>>>(
            cur, vpb,
            cnt, slots, bondA + (size_t)l * 5 * H, epsA, l,
            cw1T + (size_t)l * 1024 * 256, vw1T + (size_t)lv * 1024 * 256,
            cb1A + (size_t)l * 1024,       vb1A + (size_t)lv * 1024,
            clngA + (size_t)l * 1024,      vlngA + (size_t)lv * 1024,
            clnbA + (size_t)l * 1024,      vlnbA + (size_t)lv * 1024,
            cw2T + (size_t)l * 256 * 1024, vw2T + (size_t)lv * 256 * 1024,
            cb2A + (size_t)l * 256,        vb2A + (size_t)lv * 256,
            ngA + (size_t)l * H, nbA + (size_t)l * H,
            nxt, vn, has_vn, NBLK_NODE, has_vn);
        bf16_t* t = cur; cur = nxt; nxt = t;
    }

    k_graphsum<<<GG, 128, 0, stream>>>(cur, hgb);
    k_mlp_proj<<<GG / 32, 512, 0, stream>>>(hgb, pw1T, pb1A, plngA, plnbA, pw2T, pb2A, pout2);
    k_norm<<<GG, 256, 0, stream>>>(pout2, outz);
}